// Round 4
// baseline (227.321 us; speedup 1.0000x reference)
//
#include <hip/hip_runtime.h>
#include <cstdint>

// CTC loss, tf.nn.ctc_loss semantics (blank_index=0), B=1024 T=256 C=128 L=32.
//
// Round-12: resubmit of the R11 split design (container-level bench failure,
// no kernel evidence against it) with hardening:
//   - no negative-displaced pointers (offset-based guarded stores)
//   - 8-byte uint2 loads in the DP kernel instead of 16-byte h8 loads
//     (immune to workspace alignment), same addresses/data
//   - explicit b-range guard in kernel 2
// Rationale (R10 counters): fused kernel is latency-bound on the serial
// 255-step alpha DP concentrated on SIMD 0 (VALUBusy 26%, runtime
// independent of FETCH_SIZE -- cache-warm replays identical). Split:
//   kernel 1: block per b, 512 thr. Pure streaming softmax/gather (register
//     float4 pipeline): writes Gt[b][slot][t] (f16, transposed so DP reads
//     are contiguous in t), slotO[b][32], S[b].
//   kernel 2: 256 blocks x 256 thr; wave w of block k owns b=4k+w. One wave
//     per SIMD across the chip, zero barriers, register-prefetched reads of
//     L2/L3-resident Gt.
// Numerics bit-identical to R9/R10 (same f16 rounding, op order, partS sum
// order, epilogue). Fallback to the proven R9 fused kernel if ws too small.
// Predicted: k1 ~25-30 us (~5 TB/s), k2 ~8-14 us; dur_us 214 -> ~165-180.

#define CTC_BLANK 0
#define CTC_PAD   127
#define NEG       (-1e30f)
#define LOG2E     1.44269504088896340736f
#define LN2       0.69314718055994530942f

constexpr int Bn = 1024, Tn = 256, Cn = 128, Ln = 32;
constexpr int NSLOT = Ln + 1;      // 33 used slots (blank + 32 labels)
constexpr int GSLOT = 34;          // padded slot count in workspace
constexpr int GT_B  = GSLOT * Tn;  // 8704 f16 per batch element

// workspace layout (bytes)
constexpr size_t WS_GT   = 0;
constexpr size_t WS_SLOT = (size_t)Bn * GT_B * 2;           // 17,825,792
constexpr size_t WS_S    = WS_SLOT + (size_t)Bn * Ln * 4;   // +131,072
constexpr size_t WS_NEED = WS_S + (size_t)Bn * 4;           // +4,096

__device__ __forceinline__ float fexp2(float x) { return __builtin_amdgcn_exp2f(x); }
__device__ __forceinline__ float flog2(float x) { return __builtin_amdgcn_logf(x); }

// s += dpp_shift(s); invalid source lanes contribute 0 (bound_ctrl:0).
template <int CTRL>
__device__ __forceinline__ float dpp_add(float s) {
    int v = __builtin_amdgcn_update_dpp(0, __float_as_int(s), CTRL, 0xF, 0xF, true);
    return s + __int_as_float(v);
}
// lane i <- src[lane i-1]; lane 0 <- old.  (wave_shr:1, VALU pipe)
__device__ __forceinline__ float dpp_wave_shr1(float src, float old) {
    return __int_as_float(__builtin_amdgcn_update_dpp(
        __float_as_int(old), __float_as_int(src), 0x138, 0xF, 0xF, false));
}
// async global->LDS, 16 B/lane (fallback kernel only)
__device__ __forceinline__ void gl_lds16(const float* g, float* l) {
    __builtin_amdgcn_global_load_lds(
        (const __attribute__((address_space(1))) uint32_t*)g,
        (__attribute__((address_space(3))) uint32_t*)l, 16, 0, 0);
}

// ---------------------------------------------------------------------------
// Kernel 1: streaming softmax + gather. Block b, 512 threads, no DP.
// ---------------------------------------------------------------------------
__global__ __launch_bounds__(512, 8) void ctc_softmax_kernel(
        const int*   __restrict__ y_true,   // [B, L]
        const float* __restrict__ y_pred,   // [B, T, C]
        _Float16*    __restrict__ Gt,       // [B, GSLOT, T]  log2-domain
        int*         __restrict__ slotO_arr,// [B, L]
        float*       __restrict__ Sglob)    // [B]
{
    __shared__ int labels[Ln];
    __shared__ __align__(16) int cmap[Cn];
    __shared__ int used[Cn];
    __shared__ int wcnt[8];
    __shared__ float partS[16];

    const int b    = blockIdx.x;
    const int tid  = threadIdx.x;
    const int lane = tid & 63;
    const int wave = tid >> 6;
    const int half = lane >> 5;
    const int l32  = lane & 31;

    // issue the first 4 chunk loads immediately; latency hides under the
    // cmap build (its __syncthreads completes them into registers)
    const float4* gsrc = (const float4*)(y_pred + (size_t)b * Tn * Cn);
    float4 xr0 = gsrc[tid];
    float4 xr1 = gsrc[512  + tid];
    float4 xr2 = gsrc[1024 + tid];
    float4 xr3 = gsrc[1536 + tid];

    // ---- class->slot map (identical to fused version) ----
    if (tid < Ln) labels[tid] = y_true[b * Ln + tid];
    if (tid < Cn) used[tid] = 0;
    __syncthreads();
    if (tid == 0) used[CTC_BLANK] = 1;
    if (tid < Ln) used[labels[tid]] = 1;   // racy same-value writes: fine
    __syncthreads();
    {
        bool f = (tid < Cn) && (used[tid] != 0);
        unsigned long long m = __ballot(f);
        if (lane == 0) wcnt[wave] = __popcll(m);
        __syncthreads();
        int base = 0;
        for (int w = 0; w < wave; ++w) base += wcnt[w];
        if (tid < Cn)
            cmap[tid] = f ? (base + __popcll(m & ((1ull << lane) - 1ull))) : -1;
        __syncthreads();
    }

    const int4 cm = ((const int4*)cmap)[l32];
    _Float16* gt = Gt + (size_t)b * GT_B;
    const int rbase = tid >> 5;            // == 2*wave + half, 0..15
    float acc = 0.f;   // log2-domain partial lse sum

    #pragma unroll
    for (int j = 0; j < 16; ++j) {
        float4 x;
        if      ((j & 3) == 0) x = xr0;
        else if ((j & 3) == 1) x = xr1;
        else if ((j & 3) == 2) x = xr2;
        else                   x = xr3;
        if (j + 4 < 16) {                  // refill ring slot (static index)
            float4 nx = gsrc[(j + 4) * 512 + tid];
            if      ((j & 3) == 0) xr0 = nx;
            else if ((j & 3) == 1) xr1 = nx;
            else if ((j & 3) == 2) xr2 = nx;
            else                   xr3 = nx;
        }
        const float e0 = x.x * LOG2E, e1 = x.y * LOG2E,
                    e2 = x.z * LOG2E, e3 = x.w * LOG2E;
        const int tcol = j * 16 + rbase;   // t index this thread owns
        if (cm.x >= 0) gt[cm.x * Tn + tcol] = (_Float16)e0;
        if (cm.y >= 0) gt[cm.y * Tn + tcol] = (_Float16)e1;
        if (cm.z >= 0) gt[cm.z * Tn + tcol] = (_Float16)e2;
        if (cm.w >= 0) gt[cm.w * Tn + tcol] = (_Float16)e3;
        float s = fexp2(e0) + fexp2(e1) + fexp2(e2) + fexp2(e3);
        s = dpp_add<0x111>(s);   // row_shr:1
        s = dpp_add<0x112>(s);   // row_shr:2
        s = dpp_add<0x114>(s);   // row_shr:4
        s = dpp_add<0x118>(s);   // row_shr:8
        s = dpp_add<0x142>(s);   // row_bcast:15
        acc += flog2(s);         // valid on lanes 31 / 63 (log2 domain)
    }
    if (l32 == 31) partS[wave * 2 + half] = acc;
    if (tid < Ln) slotO_arr[b * Ln + tid] = cmap[labels[tid]];
    __syncthreads();
    if (tid == 0) {
        float S = 0.f;
        #pragma unroll
        for (int j = 0; j < 16; ++j) S += partS[j];   // same order as fused
        Sglob[b] = S;
    }
}

// ---------------------------------------------------------------------------
// Kernel 2: alpha DP. 256 blocks x 256 thr; wave w of block k owns b=4k+w.
// One wave per SIMD across the whole chip; zero barriers.
// ---------------------------------------------------------------------------
typedef __attribute__((ext_vector_type(4))) _Float16 h4;

__global__ __launch_bounds__(256) void ctc_dp_kernel(
        const int*      __restrict__ y_true,
        const _Float16* __restrict__ Gt,
        const int*      __restrict__ slotO_arr,
        const float*    __restrict__ Sglob,
        float*          __restrict__ out)
{
    const int wave = threadIdx.x >> 6;
    const int i    = threadIdx.x & 63;          // lane: states 2i, 2i+1
    const int b    = blockIdx.x * 4 + wave;
    if (b >= Bn) return;

    const bool validO = (i < Ln);
    const bool validE = (i <= Ln);
    const int  myLab   = validO ? y_true[b * Ln + i] : -1;
    const int  prevLab = (i >= 1 && i < Ln) ? y_true[b * Ln + i - 1] : -1;
    const int  slotO   = validO ? slotO_arr[b * Ln + i] : 0;
    const bool skipO   = (i >= 1 && i < Ln) &&
                         (myLab != CTC_BLANK) && (myLab != prevLab);
    const int  len = __popcll(__ballot(validO && (myLab != CTC_PAD)));

    const _Float16* gB = Gt + (size_t)b * GT_B;     // blank is always slot 0
    const _Float16* gO = gB + slotO * Tn;           // slotO >= 0 always

    float aE = (i == 0) ? (float)gB[0] : NEG;       // t = 0 init
    float aO = (i == 0) ? (float)gO[0] : NEG;

    auto step = [&](float lpB, float lpO) {
        const float aOup = dpp_wave_shr1(aO, NEG);   // alpha[2i-1]
        const float m  = fmaxf(aE, aOup);
        const float e1 = fexp2(aE - m);
        const float e2 = fexp2(aOup - m);
        const float sE = e1 + e2;
        const float nE = lpB + m + flog2(sE);                // s = 2i
        const float m3 = fmaxf(aO, m);
        const float nO = lpO + m3 +                          // s = 2i+1
            flog2(fexp2(aO - m3) + (skipO ? sE : e1) * fexp2(m - m3));
        aE = validE ? nE : NEG;
        aO = validO ? nO : NEG;
    };

    // 8-t groups, register-prefetched via two 8-byte loads each (4 f16/load)
    h4 vB0 = *(const h4*)(gB),     vB1 = *(const h4*)(gB + 4);
    h4 vO0 = *(const h4*)(gO),     vO1 = *(const h4*)(gO + 4);
    {   // group 0: t = 1..7 (t = 0 consumed by init)
        h4 nB0 = *(const h4*)(gB + 8),  nB1 = *(const h4*)(gB + 12);
        h4 nO0 = *(const h4*)(gO + 8),  nO1 = *(const h4*)(gO + 12);
        #pragma unroll
        for (int k = 1; k < 4; ++k) step((float)vB0[k], (float)vO0[k]);
        #pragma unroll
        for (int k = 0; k < 4; ++k) step((float)vB1[k], (float)vO1[k]);
        vB0 = nB0; vB1 = nB1; vO0 = nO0; vO1 = nO1;
    }
    for (int g = 1; g < 31; ++g) {   // groups 1..30, prefetch next
        h4 nB0 = *(const h4*)(gB + 8 * (g + 1));
        h4 nB1 = *(const h4*)(gB + 8 * (g + 1) + 4);
        h4 nO0 = *(const h4*)(gO + 8 * (g + 1));
        h4 nO1 = *(const h4*)(gO + 8 * (g + 1) + 4);
        #pragma unroll
        for (int k = 0; k < 4; ++k) step((float)vB0[k], (float)vO0[k]);
        #pragma unroll
        for (int k = 0; k < 4; ++k) step((float)vB1[k], (float)vO1[k]);
        vB0 = nB0; vB1 = nB1; vO0 = nO0; vO1 = nO1;
    }
    #pragma unroll
    for (int k = 0; k < 4; ++k) step((float)vB0[k], (float)vO0[k]);  // group 31
    #pragma unroll
    for (int k = 0; k < 4; ++k) step((float)vB1[k], (float)vO1[k]);

    const float v1 = __shfl(aE, len, 64);       // alpha[2*len]
    const float v2 = __shfl(aO, len - 1, 64);   // alpha[2*len-1]
    if (i == 0) {
        const float S  = Sglob[b];
        const float mm = fmaxf(v1, v2);
        const float L2 = mm + flog2(fexp2(v1 - mm) + fexp2(v2 - mm));
        out[b] = LN2 * (S - L2);   // both terms log2-domain
    }
}

// ---------------------------------------------------------------------------
// Fallback: R9 fused kernel (used only if ws_size < WS_NEED)
// ---------------------------------------------------------------------------
constexpr int CR  = 16;
constexpr int NCH = Tn / CR;
constexpr int CF  = CR * Cn;

__global__ __launch_bounds__(512, 8) void ctc_fused_fallback(
        const int*   __restrict__ y_true,
        const float* __restrict__ y_pred,
        float*       __restrict__ out)
{
    __shared__ __align__(16) float raw[2][CF];
    __shared__ _Float16 Gc[Tn * NSLOT];
    __shared__ int   labels[Ln];
    __shared__ __align__(16) int cmap[Cn];
    __shared__ int   used[Cn];
    __shared__ int   wcnt[8];
    __shared__ float partS[16];

    const int b    = blockIdx.x;
    const int tid  = threadIdx.x;
    const int lane = tid & 63;
    const int wave = tid >> 6;

    const float* gbase = y_pred + (size_t)b * Tn * Cn;
    auto stage = [&](int c, int buf) {
        gl_lds16(gbase + c * CF + tid * 4, &raw[buf][wave * 256]);
    };
    stage(0, 0);

    if (tid < Ln) labels[tid] = y_true[b * Ln + tid];
    if (tid < Cn) used[tid] = 0;
    __syncthreads();
    if (tid == 0) used[CTC_BLANK] = 1;
    if (tid < Ln) used[labels[tid]] = 1;
    __syncthreads();
    {
        bool f = (tid < Cn) && (used[tid] != 0);
        unsigned long long m = __ballot(f);
        if (lane == 0) wcnt[wave] = __popcll(m);
        __syncthreads();
        int base = 0;
        for (int w = 0; w < wave; ++w) base += wcnt[w];
        if (tid < Cn)
            cmap[tid] = f ? (base + __popcll(m & ((1ull << lane) - 1ull))) : -1;
        __syncthreads();
    }

    const int half = lane >> 5;
    const int l32  = lane & 31;
    const int4 cm  = ((const int4*)cmap)[l32];
    float acc = 0.f;

    const int  i      = lane;
    const bool validO = (i < Ln);
    const bool validE = (i <= Ln);
    const int  myLab   = validO ? labels[i] : -1;
    const int  prevLab = (i >= 1 && i < Ln) ? labels[i - 1] : -1;
    const int  slotO   = validO ? cmap[myLab] : 0;
    const bool skipO   = (i >= 1 && i < Ln) &&
                         (myLab != CTC_BLANK) && (myLab != prevLab);
    const int  len = __popcll(__ballot(validO && (myLab != CTC_PAD)));
    float aE = NEG, aO = NEG;

    auto dp_chunk = [&](int t0, int t1) {
        int t = t0;
        if (t == 0) {
            aE = (i == 0) ? (float)Gc[0]     : NEG;
            aO = (i == 0) ? (float)Gc[slotO] : NEG;
            t = 1;
        }
        float pB[2], pO[2];
        const int ta = t, tb = (t + 1 < t1) ? t + 1 : t1 - 1;
        pB[0] = (float)Gc[ta * NSLOT]; pO[0] = (float)Gc[ta * NSLOT + slotO];
        pB[1] = (float)Gc[tb * NSLOT]; pO[1] = (float)Gc[tb * NSLOT + slotO];
        int k = 0;
        #pragma unroll 2
        for (; t < t1; ++t) {
            const float lpB = pB[k], lpO = pO[k];
            const int tp = (t + 2 < t1) ? t + 2 : t1 - 1;
            pB[k] = (float)Gc[tp * NSLOT];
            pO[k] = (float)Gc[tp * NSLOT + slotO];
            k ^= 1;
            const float aOup = dpp_wave_shr1(aO, NEG);
            const float m  = fmaxf(aE, aOup);
            const float e1 = fexp2(aE - m);
            const float e2 = fexp2(aOup - m);
            const float sE = e1 + e2;
            const float nE = lpB + m + flog2(sE);
            const float m3 = fmaxf(aO, m);
            const float nO = lpO + m3 +
                flog2(fexp2(aO - m3) + (skipO ? sE : e1) * fexp2(m - m3));
            aE = validE ? nE : NEG;
            aO = validO ? nO : NEG;
        }
    };

    for (int c = 0; c < NCH; ++c) {
        if (c + 1 < NCH) stage(c + 1, (c + 1) & 1);
        if (wave == 0 && c > 0) dp_chunk((c - 1) * CR, c * CR);
        __builtin_amdgcn_sched_barrier(0);
        if (c + 1 < NCH) asm volatile("s_waitcnt vmcnt(1)" ::: "memory");
        else             asm volatile("s_waitcnt vmcnt(0)" ::: "memory");
        __builtin_amdgcn_sched_barrier(0);
        {
            const int rl = 2 * wave + half;
            const int r  = c * CR + rl;
            const float4 x = ((const float4*)&raw[c & 1][rl * Cn])[l32];
            const float e0 = x.x * LOG2E, e1 = x.y * LOG2E,
                        e2 = x.z * LOG2E, e3 = x.w * LOG2E;
            if (cm.x >= 0) Gc[r * NSLOT + cm.x] = (_Float16)e0;
            if (cm.y >= 0) Gc[r * NSLOT + cm.y] = (_Float16)e1;
            if (cm.z >= 0) Gc[r * NSLOT + cm.z] = (_Float16)e2;
            if (cm.w >= 0) Gc[r * NSLOT + cm.w] = (_Float16)e3;
            float s = fexp2(e0) + fexp2(e1) + fexp2(e2) + fexp2(e3);
            s = dpp_add<0x111>(s);
            s = dpp_add<0x112>(s);
            s = dpp_add<0x114>(s);
            s = dpp_add<0x118>(s);
            s = dpp_add<0x142>(s);
            acc += flog2(s);
        }
        if (c == NCH - 1 && l32 == 31) partS[wave * 2 + half] = acc;
        asm volatile("s_waitcnt lgkmcnt(0)" ::: "memory");
        __builtin_amdgcn_s_barrier();
    }

    if (wave == 0) {
        dp_chunk(Tn - CR, Tn);
        const float v1 = __shfl(aE, len, 64);
        const float v2 = __shfl(aO, len - 1, 64);
        if (i == 0) {
            float S = 0.f;
            #pragma unroll
            for (int j = 0; j < 16; ++j) S += partS[j];
            const float mm = fmaxf(v1, v2);
            const float L2 = mm + flog2(fexp2(v1 - mm) + fexp2(v2 - mm));
            out[b] = LN2 * (S - L2);
        }
    }
}

extern "C" void kernel_launch(void* const* d_in, const int* in_sizes, int n_in,
                              void* d_out, int out_size, void* d_ws, size_t ws_size,
                              hipStream_t stream) {
    const int*   y_true = (const int*)d_in[0];
    const float* y_pred = (const float*)d_in[1];
    float*       out    = (float*)d_out;
    if (d_ws != nullptr && ws_size >= WS_NEED) {
        _Float16* Gt    = (_Float16*)((char*)d_ws + WS_GT);
        int*      slotO = (int*)((char*)d_ws + WS_SLOT);
        float*    Sg    = (float*)((char*)d_ws + WS_S);
        ctc_softmax_kernel<<<Bn, 512, 0, stream>>>(y_true, y_pred, Gt, slotO, Sg);
        ctc_dp_kernel<<<Bn / 4, 256, 0, stream>>>(y_true, Gt, slotO, Sg, out);
    } else {
        ctc_fused_fallback<<<Bn, 512, 0, stream>>>(y_true, y_pred, out);
    }
}

// Round 5
// 214.781 us; speedup vs baseline: 1.0584x; 1.0584x over previous
//
#include <hip/hip_runtime.h>
#include <cstdint>

// CTC loss, tf.nn.ctc_loss semantics (blank_index=0), B=1024 T=256 C=128 L=32.
//
// Round-13: R12's split regressed (+25 us vs fused) because k1's transposed
// gather stores were 2-byte writes at 512-B lane stride (64 lines per store
// instruction, ~524K scattered store instrs). Fix: k1 stages the gather in
// LDS exactly like the proven fused kernel (Gc[256][34], bank-friendly),
// then does ONE coalesced transpose pass:
//   - LDS reads GcU[(tc*16+k)*34 + s]: bank=(17t + s/2)%32 -> 2-way (free)
//   - global stores: blocked layout Gt[b][tc][slot][tt] (tc=t>>4,tt=t&15);
//     thread (tc=tid>>5, s=tid&31) writes 32 B contiguous; consecutive
//     lanes contiguous -> 1 KB/half-wave fully coalesced.
// k2 reads each 8-t group as one aligned 16-B h8 load per operand (t runs
// contiguous within a 16-t block). Step order unchanged -> bit-identical.
// Predicted: k1 ~22-28 us (read-BW bound), k2 ~6-10 us; dur_us 227 -> ~188.

#define CTC_BLANK 0
#define CTC_PAD   127
#define NEG       (-1e30f)
#define LOG2E     1.44269504088896340736f
#define LN2       0.69314718055994530942f

constexpr int Bn = 1024, Tn = 256, Cn = 128, Ln = 32;
constexpr int NSLOT = Ln + 1;      // 33 used slots (blank + 32 labels)
constexpr int GS    = 34;          // padded slot stride
constexpr int GT_B  = 16 * GS * 16;  // 8704 f16 per batch element ([tc][s][tt])

// workspace layout (bytes)
constexpr size_t WS_GT   = 0;
constexpr size_t WS_SLOT = (size_t)Bn * GT_B * 2;           // 17,825,792
constexpr size_t WS_S    = WS_SLOT + (size_t)Bn * Ln * 4;   // +131,072
constexpr size_t WS_NEED = WS_S + (size_t)Bn * 4;           // +4,096

__device__ __forceinline__ float fexp2(float x) { return __builtin_amdgcn_exp2f(x); }
__device__ __forceinline__ float flog2(float x) { return __builtin_amdgcn_logf(x); }

// s += dpp_shift(s); invalid source lanes contribute 0 (bound_ctrl:0).
template <int CTRL>
__device__ __forceinline__ float dpp_add(float s) {
    int v = __builtin_amdgcn_update_dpp(0, __float_as_int(s), CTRL, 0xF, 0xF, true);
    return s + __int_as_float(v);
}
// lane i <- src[lane i-1]; lane 0 <- old.  (wave_shr:1, VALU pipe)
__device__ __forceinline__ float dpp_wave_shr1(float src, float old) {
    return __int_as_float(__builtin_amdgcn_update_dpp(
        __float_as_int(old), __float_as_int(src), 0x138, 0xF, 0xF, false));
}
// async global->LDS, 16 B/lane (fallback kernel only)
__device__ __forceinline__ void gl_lds16(const float* g, float* l) {
    __builtin_amdgcn_global_load_lds(
        (const __attribute__((address_space(1))) uint32_t*)g,
        (__attribute__((address_space(3))) uint32_t*)l, 16, 0, 0);
}

// ---------------------------------------------------------------------------
// Kernel 1: streaming softmax + gather -> LDS -> coalesced transpose out.
// ---------------------------------------------------------------------------
__global__ __launch_bounds__(512, 8) void ctc_softmax_kernel(
        const int*   __restrict__ y_true,   // [B, L]
        const float* __restrict__ y_pred,   // [B, T, C]
        _Float16*    __restrict__ Gt,       // [B][tc][s][tt]  log2-domain
        int*         __restrict__ slotO_arr,// [B, L]
        float*       __restrict__ Sglob)    // [B]
{
    __shared__ _Float16 Gc[Tn * GS];       // 17.4 KB, [t][slot]
    __shared__ int labels[Ln];
    __shared__ __align__(16) int cmap[Cn];
    __shared__ int used[Cn];
    __shared__ int wcnt[8];
    __shared__ float partS[16];

    const int b    = blockIdx.x;
    const int tid  = threadIdx.x;
    const int lane = tid & 63;
    const int wave = tid >> 6;
    const int half = lane >> 5;
    const int l32  = lane & 31;

    // issue the first 4 chunk loads immediately; latency hides under the
    // cmap build (its __syncthreads completes them into registers)
    const float4* gsrc = (const float4*)(y_pred + (size_t)b * Tn * Cn);
    float4 xr0 = gsrc[tid];
    float4 xr1 = gsrc[512  + tid];
    float4 xr2 = gsrc[1024 + tid];
    float4 xr3 = gsrc[1536 + tid];

    // ---- class->slot map (identical to fused version) ----
    if (tid < Ln) labels[tid] = y_true[b * Ln + tid];
    if (tid < Cn) used[tid] = 0;
    __syncthreads();
    if (tid == 0) used[CTC_BLANK] = 1;
    if (tid < Ln) used[labels[tid]] = 1;   // racy same-value writes: fine
    __syncthreads();
    {
        bool f = (tid < Cn) && (used[tid] != 0);
        unsigned long long m = __ballot(f);
        if (lane == 0) wcnt[wave] = __popcll(m);
        __syncthreads();
        int base = 0;
        for (int w = 0; w < wave; ++w) base += wcnt[w];
        if (tid < Cn)
            cmap[tid] = f ? (base + __popcll(m & ((1ull << lane) - 1ull))) : -1;
        __syncthreads();
    }

    const int4 cm = ((const int4*)cmap)[l32];
    const int rbase = tid >> 5;            // 0..15: t-offset within 16-t group
    float acc = 0.f;   // log2-domain partial lse sum

    #pragma unroll
    for (int j = 0; j < 16; ++j) {
        float4 x;
        if      ((j & 3) == 0) x = xr0;
        else if ((j & 3) == 1) x = xr1;
        else if ((j & 3) == 2) x = xr2;
        else                   x = xr3;
        if (j + 4 < 16) {                  // refill ring slot (static index)
            float4 nx = gsrc[(j + 4) * 512 + tid];
            if      ((j & 3) == 0) xr0 = nx;
            else if ((j & 3) == 1) xr1 = nx;
            else if ((j & 3) == 2) xr2 = nx;
            else                   xr3 = nx;
        }
        const float e0 = x.x * LOG2E, e1 = x.y * LOG2E,
                    e2 = x.z * LOG2E, e3 = x.w * LOG2E;
        const int tcol = j * 16 + rbase;   // t index this thread owns
        if (cm.x >= 0) Gc[tcol * GS + cm.x] = (_Float16)e0;
        if (cm.y >= 0) Gc[tcol * GS + cm.y] = (_Float16)e1;
        if (cm.z >= 0) Gc[tcol * GS + cm.z] = (_Float16)e2;
        if (cm.w >= 0) Gc[tcol * GS + cm.w] = (_Float16)e3;
        float s = fexp2(e0) + fexp2(e1) + fexp2(e2) + fexp2(e3);
        s = dpp_add<0x111>(s);   // row_shr:1
        s = dpp_add<0x112>(s);   // row_shr:2
        s = dpp_add<0x114>(s);   // row_shr:4
        s = dpp_add<0x118>(s);   // row_shr:8
        s = dpp_add<0x142>(s);   // row_bcast:15
        acc += flog2(s);         // valid on lanes 31 / 63 (log2 domain)
    }
    if (l32 == 31) partS[wave * 2 + half] = acc;
    if (tid < Ln) slotO_arr[b * Ln + tid] = cmap[labels[tid]];
    __syncthreads();

    // ---- coalesced transpose: Gc[t][s] -> Gt[b][tc][s][tt] ----
    {
        const uint16_t* GcU = (const uint16_t*)Gc;
        const int tc = tid >> 5;                  // 0..15
        for (int s = (tid & 31); s < NSLOT; s += 32) {
            uint32_t w[8];
            #pragma unroll
            for (int k = 0; k < 8; ++k) {
                const uint32_t lo = GcU[(tc * 16 + 2 * k)     * GS + s];
                const uint32_t hi = GcU[(tc * 16 + 2 * k + 1) * GS + s];
                w[k] = lo | (hi << 16);
            }
            uint4* dst = (uint4*)(Gt + (size_t)b * GT_B + tc * (GS * 16) + s * 16);
            dst[0] = make_uint4(w[0], w[1], w[2], w[3]);
            dst[1] = make_uint4(w[4], w[5], w[6], w[7]);
        }
    }
    if (tid == 0) {
        float S = 0.f;
        #pragma unroll
        for (int j = 0; j < 16; ++j) S += partS[j];   // same order as fused
        Sglob[b] = S;
    }
}

// ---------------------------------------------------------------------------
// Kernel 2: alpha DP. 256 blocks x 256 thr; wave w of block k owns b=4k+w.
// One wave per SIMD across the whole chip; zero barriers.
// ---------------------------------------------------------------------------
typedef __attribute__((ext_vector_type(8))) _Float16 h8;

__global__ __launch_bounds__(256) void ctc_dp_kernel(
        const int*      __restrict__ y_true,
        const _Float16* __restrict__ Gt,
        const int*      __restrict__ slotO_arr,
        const float*    __restrict__ Sglob,
        float*          __restrict__ out)
{
    const int wave = threadIdx.x >> 6;
    const int i    = threadIdx.x & 63;          // lane: states 2i, 2i+1
    const int b    = blockIdx.x * 4 + wave;
    if (b >= Bn) return;

    const bool validO = (i < Ln);
    const bool validE = (i <= Ln);
    const int  myLab   = validO ? y_true[b * Ln + i] : -1;
    const int  prevLab = (i >= 1 && i < Ln) ? y_true[b * Ln + i - 1] : -1;
    const int  slotO   = validO ? slotO_arr[b * Ln + i] : 0;
    const bool skipO   = (i >= 1 && i < Ln) &&
                         (myLab != CTC_BLANK) && (myLab != prevLab);
    const int  len = __popcll(__ballot(validO && (myLab != CTC_PAD)));

    // layout: Gt[b][tc][s][tt], flat f16 index = b*GT_B + tc*544 + s*16 + tt
    const _Float16* gB = Gt + (size_t)b * GT_B;
    const int oOff = slotO * 16;                // slot row offset (f16 units)

    float aE = (i == 0) ? (float)gB[0]    : NEG;   // t = 0 init
    float aO = (i == 0) ? (float)gB[oOff] : NEG;

    auto step = [&](float lpB, float lpO) {
        const float aOup = dpp_wave_shr1(aO, NEG);   // alpha[2i-1]
        const float m  = fmaxf(aE, aOup);
        const float e1 = fexp2(aE - m);
        const float e2 = fexp2(aOup - m);
        const float sE = e1 + e2;
        const float nE = lpB + m + flog2(sE);                // s = 2i
        const float m3 = fmaxf(aO, m);
        const float nO = lpO + m3 +                          // s = 2i+1
            flog2(fexp2(aO - m3) + (skipO ? sE : e1) * fexp2(m - m3));
        aE = validE ? nE : NEG;
        aO = validO ? nO : NEG;
    };

    // 8-t group g covers t = 8g..8g+7: tc = g>>1, tt = 8*(g&1)..+7 ->
    // one aligned 16-B h8 load per operand (16-B aligned: all terms %8==0)
    auto ldB = [&](int g) -> h8 {
        return *(const h8*)(gB + (g >> 1) * (GS * 16) + (g & 1) * 8);
    };
    auto ldO = [&](int g) -> h8 {
        return *(const h8*)(gB + oOff + (g >> 1) * (GS * 16) + (g & 1) * 8);
    };

    h8 vB = ldB(0), vO = ldO(0);
    {   // group 0: t = 1..7 (t = 0 consumed by init)
        h8 nB = ldB(1), nO8 = ldO(1);
        #pragma unroll
        for (int k = 1; k < 8; ++k) step((float)vB[k], (float)vO[k]);
        vB = nB; vO = nO8;
    }
    for (int g = 1; g < 31; ++g) {   // groups 1..30, prefetch next
        h8 nB = ldB(g + 1), nO8 = ldO(g + 1);
        #pragma unroll
        for (int k = 0; k < 8; ++k) step((float)vB[k], (float)vO[k]);
        vB = nB; vO = nO8;
    }
    #pragma unroll
    for (int k = 0; k < 8; ++k) step((float)vB[k], (float)vO[k]);  // group 31

    const float v1 = __shfl(aE, len, 64);       // alpha[2*len]
    const float v2 = __shfl(aO, len - 1, 64);   // alpha[2*len-1]
    if (i == 0) {
        const float S  = Sglob[b];
        const float mm = fmaxf(v1, v2);
        const float L2 = mm + flog2(fexp2(v1 - mm) + fexp2(v2 - mm));
        out[b] = LN2 * (S - L2);   // both terms log2-domain
    }
}

// ---------------------------------------------------------------------------
// Fallback: R9 fused kernel (used only if ws_size < WS_NEED)
// ---------------------------------------------------------------------------
constexpr int CR  = 16;
constexpr int NCH = Tn / CR;
constexpr int CF  = CR * Cn;

__global__ __launch_bounds__(512, 8) void ctc_fused_fallback(
        const int*   __restrict__ y_true,
        const float* __restrict__ y_pred,
        float*       __restrict__ out)
{
    __shared__ __align__(16) float raw[2][CF];
    __shared__ _Float16 Gc[Tn * NSLOT];
    __shared__ int   labels[Ln];
    __shared__ __align__(16) int cmap[Cn];
    __shared__ int   used[Cn];
    __shared__ int   wcnt[8];
    __shared__ float partS[16];

    const int b    = blockIdx.x;
    const int tid  = threadIdx.x;
    const int lane = tid & 63;
    const int wave = tid >> 6;

    const float* gbase = y_pred + (size_t)b * Tn * Cn;
    auto stage = [&](int c, int buf) {
        gl_lds16(gbase + c * CF + tid * 4, &raw[buf][wave * 256]);
    };
    stage(0, 0);

    if (tid < Ln) labels[tid] = y_true[b * Ln + tid];
    if (tid < Cn) used[tid] = 0;
    __syncthreads();
    if (tid == 0) used[CTC_BLANK] = 1;
    if (tid < Ln) used[labels[tid]] = 1;
    __syncthreads();
    {
        bool f = (tid < Cn) && (used[tid] != 0);
        unsigned long long m = __ballot(f);
        if (lane == 0) wcnt[wave] = __popcll(m);
        __syncthreads();
        int base = 0;
        for (int w = 0; w < wave; ++w) base += wcnt[w];
        if (tid < Cn)
            cmap[tid] = f ? (base + __popcll(m & ((1ull << lane) - 1ull))) : -1;
        __syncthreads();
    }

    const int half = lane >> 5;
    const int l32  = lane & 31;
    const int4 cm  = ((const int4*)cmap)[l32];
    float acc = 0.f;

    const int  i      = lane;
    const bool validO = (i < Ln);
    const bool validE = (i <= Ln);
    const int  myLab   = validO ? labels[i] : -1;
    const int  prevLab = (i >= 1 && i < Ln) ? labels[i - 1] : -1;
    const int  slotO   = validO ? cmap[myLab] : 0;
    const bool skipO   = (i >= 1 && i < Ln) &&
                         (myLab != CTC_BLANK) && (myLab != prevLab);
    const int  len = __popcll(__ballot(validO && (myLab != CTC_PAD)));
    float aE = NEG, aO = NEG;

    auto dp_chunk = [&](int t0, int t1) {
        int t = t0;
        if (t == 0) {
            aE = (i == 0) ? (float)Gc[0]     : NEG;
            aO = (i == 0) ? (float)Gc[slotO] : NEG;
            t = 1;
        }
        float pB[2], pO[2];
        const int ta = t, tb = (t + 1 < t1) ? t + 1 : t1 - 1;
        pB[0] = (float)Gc[ta * NSLOT]; pO[0] = (float)Gc[ta * NSLOT + slotO];
        pB[1] = (float)Gc[tb * NSLOT]; pO[1] = (float)Gc[tb * NSLOT + slotO];
        int k = 0;
        #pragma unroll 2
        for (; t < t1; ++t) {
            const float lpB = pB[k], lpO = pO[k];
            const int tp = (t + 2 < t1) ? t + 2 : t1 - 1;
            pB[k] = (float)Gc[tp * NSLOT];
            pO[k] = (float)Gc[tp * NSLOT + slotO];
            k ^= 1;
            const float aOup = dpp_wave_shr1(aO, NEG);
            const float m  = fmaxf(aE, aOup);
            const float e1 = fexp2(aE - m);
            const float e2 = fexp2(aOup - m);
            const float sE = e1 + e2;
            const float nE = lpB + m + flog2(sE);
            const float m3 = fmaxf(aO, m);
            const float nO = lpO + m3 +
                flog2(fexp2(aO - m3) + (skipO ? sE : e1) * fexp2(m - m3));
            aE = validE ? nE : NEG;
            aO = validO ? nO : NEG;
        }
    };

    for (int c = 0; c < NCH; ++c) {
        if (c + 1 < NCH) stage(c + 1, (c + 1) & 1);
        if (wave == 0 && c > 0) dp_chunk((c - 1) * CR, c * CR);
        __builtin_amdgcn_sched_barrier(0);
        if (c + 1 < NCH) asm volatile("s_waitcnt vmcnt(1)" ::: "memory");
        else             asm volatile("s_waitcnt vmcnt(0)" ::: "memory");
        __builtin_amdgcn_sched_barrier(0);
        {
            const int rl = 2 * wave + half;
            const int r  = c * CR + rl;
            const float4 x = ((const float4*)&raw[c & 1][rl * Cn])[l32];
            const float e0 = x.x * LOG2E, e1 = x.y * LOG2E,
                        e2 = x.z * LOG2E, e3 = x.w * LOG2E;
            if (cm.x >= 0) Gc[r * NSLOT + cm.x] = (_Float16)e0;
            if (cm.y >= 0) Gc[r * NSLOT + cm.y] = (_Float16)e1;
            if (cm.z >= 0) Gc[r * NSLOT + cm.z] = (_Float16)e2;
            if (cm.w >= 0) Gc[r * NSLOT + cm.w] = (_Float16)e3;
            float s = fexp2(e0) + fexp2(e1) + fexp2(e2) + fexp2(e3);
            s = dpp_add<0x111>(s);
            s = dpp_add<0x112>(s);
            s = dpp_add<0x114>(s);
            s = dpp_add<0x118>(s);
            s = dpp_add<0x142>(s);
            acc += flog2(s);
        }
        if (c == NCH - 1 && l32 == 31) partS[wave * 2 + half] = acc;
        asm volatile("s_waitcnt lgkmcnt(0)" ::: "memory");
        __builtin_amdgcn_s_barrier();
    }

    if (wave == 0) {
        dp_chunk(Tn - CR, Tn);
        const float v1 = __shfl(aE, len, 64);
        const float v2 = __shfl(aO, len - 1, 64);
        if (i == 0) {
            float S = 0.f;
            #pragma unroll
            for (int j = 0; j < 16; ++j) S += partS[j];
            const float mm = fmaxf(v1, v2);
            const float L2 = mm + flog2(fexp2(v1 - mm) + fexp2(v2 - mm));
            out[b] = LN2 * (S - L2);
        }
    }
}

extern "C" void kernel_launch(void* const* d_in, const int* in_sizes, int n_in,
                              void* d_out, int out_size, void* d_ws, size_t ws_size,
                              hipStream_t stream) {
    const int*   y_true = (const int*)d_in[0];
    const float* y_pred = (const float*)d_in[1];
    float*       out    = (float*)d_out;
    if (d_ws != nullptr && ws_size >= WS_NEED) {
        _Float16* Gt    = (_Float16*)((char*)d_ws + WS_GT);
        int*      slotO = (int*)((char*)d_ws + WS_SLOT);
        float*    Sg    = (float*)((char*)d_ws + WS_S);
        ctc_softmax_kernel<<<Bn, 512, 0, stream>>>(y_true, y_pred, Gt, slotO, Sg);
        ctc_dp_kernel<<<Bn / 4, 256, 0, stream>>>(y_true, Gt, slotO, Sg, out);
    } else {
        ctc_fused_fallback<<<Bn, 512, 0, stream>>>(y_true, y_pred, out);
    }
}

// Round 7
// 203.414 us; speedup vs baseline: 1.1175x; 1.0559x over previous
//
#include <hip/hip_runtime.h>
#include <cstdint>

// CTC loss, tf.nn.ctc_loss semantics (blank_index=0), B=1024 T=256 C=128 L=32.
// One block (512 thr = 8 waves) per batch element.
//
// Round-15: resubmission of R14 (container-level bench failure, same infra
// signature as R11; kernel audited sound -- no barrier divergence, correct
// per-wave vmcnt accounting, no raw/handoff races). Design rationale:
//
// R10 counters on the fused kernel: VALUBusy 26% ~= one SIMD busy; runtime
// independent of FETCH_SIZE (cache-warm replays identical). Cause: wave 0
// of every co-resident block runs ALL DP chunks, and wave 0 maps to SIMD 0
// (waves round-robin w%4). 4 blocks/CU x 255 steps x ~68 cy ~= 29 us of DP
// issue serialized on 1 of 4 SIMDs.
// Fix: rotate the DP wave per chunk -- chunk c's DP runs on wave (c+b)&7,
// alpha state handed through a 512-B LDS buffer. The existing per-chunk
// {lgkmcnt(0); s_barrier} publishes the handoff (one writer/iteration,
// reader is next iteration's DP wave). DP issue spreads over all 4 SIMDs.
// Math/op order/partS order unchanged -> bit-identical (absmax 0.0).
// Predicted: kernel ~45 -> ~30-35 us, VALUBusy 26 -> 50-65%,
// dur_us 202 -> ~187-192.

#define CTC_BLANK 0
#define CTC_PAD   127
#define NEG       (-1e30f)
#define LOG2E     1.44269504088896340736f
#define LN2       0.69314718055994530942f

constexpr int Bn = 1024, Tn = 256, Cn = 128, Ln = 32;
constexpr int NSLOT = Ln + 1;     // 33: blank + up to 32 distinct labels
constexpr int CR  = 16;           // rows per chunk
constexpr int NCH = Tn / CR;      // 16 chunks
constexpr int CF  = CR * Cn;      // 2048 floats per chunk (8 KB)

__device__ __forceinline__ float fexp2(float x) { return __builtin_amdgcn_exp2f(x); }
__device__ __forceinline__ float flog2(float x) { return __builtin_amdgcn_logf(x); }

// s += dpp_shift(s); invalid source lanes contribute 0 (bound_ctrl:0).
template <int CTRL>
__device__ __forceinline__ float dpp_add(float s) {
    int v = __builtin_amdgcn_update_dpp(0, __float_as_int(s), CTRL, 0xF, 0xF, true);
    return s + __int_as_float(v);
}
// lane i <- src[lane i-1]; lane 0 <- old.  (wave_shr:1, VALU pipe)
__device__ __forceinline__ float dpp_wave_shr1(float src, float old) {
    return __int_as_float(__builtin_amdgcn_update_dpp(
        __float_as_int(old), __float_as_int(src), 0x138, 0xF, 0xF, false));
}
// async global->LDS, 16 B/lane; lptr must be wave-uniform (lane lands at
// lptr + lane*16).
__device__ __forceinline__ void gl_lds16(const float* g, float* l) {
    __builtin_amdgcn_global_load_lds(
        (const __attribute__((address_space(1))) uint32_t*)g,
        (__attribute__((address_space(3))) uint32_t*)l, 16, 0, 0);
}

__global__ __launch_bounds__(512, 8) void ctc_fused_kernel(
        const int*   __restrict__ y_true,   // [B, L]
        const float* __restrict__ y_pred,   // [B, T, C]
        float*       __restrict__ out)      // [B]
{
    __shared__ __align__(16) float raw[2][CF];     // 16 KB raw logit chunks
    __shared__ _Float16 Gc[Tn * NSLOT];            // 16.9 KB, log2-domain
    __shared__ int   labels[Ln];
    __shared__ __align__(16) int cmap[Cn];
    __shared__ int   used[Cn];
    __shared__ int   wcnt[8];
    __shared__ float partS[16];
    __shared__ float aEs[64], aOs[64];             // DP alpha handoff (512 B)

    const int b    = blockIdx.x;
    const int tid  = threadIdx.x;
    const int lane = tid & 63;
    const int wave = tid >> 6;

    const float* gbase = y_pred + (size_t)b * Tn * Cn;

    // issue chunk c into raw[buf]: one global_load_lds per wave
    auto stage = [&](int c, int buf) {
        gl_lds16(gbase + c * CF + tid * 4, &raw[buf][wave * 256]);
    };

    stage(0, 0);   // chunk-0 latency hides behind the cmap build below

    // ---- class->slot map ----
    if (tid < Ln) labels[tid] = y_true[b * Ln + tid];
    if (tid < Cn) used[tid] = 0;
    __syncthreads();
    if (tid == 0) used[CTC_BLANK] = 1;
    if (tid < Ln) used[labels[tid]] = 1;   // racy same-value writes: fine
    __syncthreads();
    {
        bool f = (tid < Cn) && (used[tid] != 0);
        unsigned long long m = __ballot(f);
        if (lane == 0) wcnt[wave] = __popcll(m);
        __syncthreads();
        int base = 0;
        for (int w = 0; w < wave; ++w) base += wcnt[w];
        if (tid < Cn)
            cmap[tid] = f ? (base + __popcll(m & ((1ull << lane) - 1ull))) : -1;
        __syncthreads();   // also drains chunk-0 global_load_lds
    }

    // ---- per-thread processing constants ----
    const int half = lane >> 5;
    const int l32  = lane & 31;
    const int4 cm  = ((const int4*)cmap)[l32];
    float acc = 0.f;

    // ---- DP constants (uniform across waves; any wave can run a chunk) ----
    const int  i      = lane;                 // lane i: states 2i, 2i+1
    const bool validO = (i < Ln);
    const bool validE = (i <= Ln);
    const int  myLab   = validO ? labels[i] : -1;
    const int  prevLab = (i >= 1 && i < Ln) ? labels[i - 1] : -1;
    const int  slotO   = validO ? cmap[myLab] : 0;
    const bool skipO   = (i >= 1 && i < Ln) &&
                         (myLab != CTC_BLANK) && (myLab != prevLab);
    const int  len = __popcll(__ballot(validO && (myLab != CTC_PAD)));
    float aE = NEG, aO = NEG;

    // DP for [t0,t1). t0==0 initializes from Gc; otherwise resumes from the
    // LDS handoff written by the previous chunk's DP wave (published by the
    // per-chunk barrier). Writes the handoff at exit.
    auto dp_chunk = [&](int t0, int t1) {
        int t = t0;
        if (t == 0) {
            aE = (i == 0) ? (float)Gc[0]     : NEG;
            aO = (i == 0) ? (float)Gc[slotO] : NEG;
            t = 1;
        } else {
            aE = aEs[i];
            aO = aOs[i];
        }
        float pB[2], pO[2];
        const int ta = t, tb = (t + 1 < t1) ? t + 1 : t1 - 1;
        pB[0] = (float)Gc[ta * NSLOT]; pO[0] = (float)Gc[ta * NSLOT + slotO];
        pB[1] = (float)Gc[tb * NSLOT]; pO[1] = (float)Gc[tb * NSLOT + slotO];
        int k = 0;
        #pragma unroll 2
        for (; t < t1; ++t) {
            const float lpB = pB[k], lpO = pO[k];
            const int tp = (t + 2 < t1) ? t + 2 : t1 - 1;
            pB[k] = (float)Gc[tp * NSLOT];
            pO[k] = (float)Gc[tp * NSLOT + slotO];
            k ^= 1;

            const float aOup = dpp_wave_shr1(aO, NEG);   // alpha[2i-1]
            const float m  = fmaxf(aE, aOup);
            const float e1 = fexp2(aE - m);
            const float e2 = fexp2(aOup - m);
            const float sE = e1 + e2;
            const float nE = lpB + m + flog2(sE);                // s = 2i
            const float m3 = fmaxf(aO, m);
            const float nO = lpO + m3 +                          // s = 2i+1
                flog2(fexp2(aO - m3) + (skipO ? sE : e1) * fexp2(m - m3));
            aE = validE ? nE : NEG;
            aO = validO ? nO : NEG;
        }
        aEs[i] = aE;   // handoff to the next chunk's DP wave; published by
        aOs[i] = aO;   // the per-chunk {lgkmcnt(0); s_barrier}
    };

    // ---- pipelined: stage c+1 || DP c-1 (rotating wave) || process c ----
    for (int c = 0; c < NCH; ++c) {
        if (c + 1 < NCH) stage(c + 1, (c + 1) & 1);

        // chunk (c-1)'s DP on wave ((c-1)+b)&7 -> spreads issue over SIMDs
        if (c > 0 && wave == ((c - 1 + b) & 7))
            dp_chunk((c - 1) * CR, c * CR);

        // counted wait: chunk c landed; chunk c+1 stays in flight across
        // the barrier below.
        __builtin_amdgcn_sched_barrier(0);
        if (c + 1 < NCH) asm volatile("s_waitcnt vmcnt(1)" ::: "memory");
        else             asm volatile("s_waitcnt vmcnt(0)" ::: "memory");
        __builtin_amdgcn_sched_barrier(0);

        // process chunk c: wave w handles rows 2w (lanes 0-31) / 2w+1 (32-63)
        {
            const int rl = 2 * wave + half;        // 0..15 within chunk
            const int r  = c * CR + rl;
            const float4 x = ((const float4*)&raw[c & 1][rl * Cn])[l32];
            const float e0 = x.x * LOG2E, e1 = x.y * LOG2E,
                        e2 = x.z * LOG2E, e3 = x.w * LOG2E;
            if (cm.x >= 0) Gc[r * NSLOT + cm.x] = (_Float16)e0;
            if (cm.y >= 0) Gc[r * NSLOT + cm.y] = (_Float16)e1;
            if (cm.z >= 0) Gc[r * NSLOT + cm.z] = (_Float16)e2;
            if (cm.w >= 0) Gc[r * NSLOT + cm.w] = (_Float16)e3;
            float s = fexp2(e0) + fexp2(e1) + fexp2(e2) + fexp2(e3);
            s = dpp_add<0x111>(s);   // row_shr:1
            s = dpp_add<0x112>(s);   // row_shr:2
            s = dpp_add<0x114>(s);   // row_shr:4
            s = dpp_add<0x118>(s);   // row_shr:8
            s = dpp_add<0x142>(s);   // row_bcast:15
            acc += flog2(s);         // valid on lanes 31 / 63 (log2 domain)
        }
        if (c == NCH - 1 && l32 == 31) partS[wave * 2 + half] = acc;

        // publish Gc rows of c + alpha handoff WITHOUT draining vmcnt
        asm volatile("s_waitcnt lgkmcnt(0)" ::: "memory");
        __builtin_amdgcn_s_barrier();
    }

    // ---- final DP chunk + epilogue (on the rotation's last wave) ----
    if (wave == ((NCH - 1 + b) & 7)) {
        dp_chunk(Tn - CR, Tn);
        const float v1 = __shfl(aE, len, 64);       // alpha[2*len]
        const float v2 = __shfl(aO, len - 1, 64);   // alpha[2*len-1]
        if (i == 0) {
            float S = 0.f;
            #pragma unroll
            for (int j = 0; j < 16; ++j) S += partS[j];
            const float mm = fmaxf(v1, v2);
            const float L2 = mm + flog2(fexp2(v1 - mm) + fexp2(v2 - mm));
            out[b] = LN2 * (S - L2);   // S and L2 both log2-domain
        }
    }
}

extern "C" void kernel_launch(void* const* d_in, const int* in_sizes, int n_in,
                              void* d_out, int out_size, void* d_ws, size_t ws_size,
                              hipStream_t stream) {
    const int*   y_true = (const int*)d_in[0];
    const float* y_pred = (const float*)d_in[1];
    float*       out    = (float*)d_out;
    ctc_fused_kernel<<<Bn, 512, 0, stream>>>(y_true, y_pred, out);
}